// Round 8
// baseline (2672.553 us; speedup 1.0000x reference)
//
#include <hip/hip_runtime.h>
#include <hip/hip_fp16.h>

#define NB     64        // batch
#define NNODES 200000
#define NSTEPS 6
#define NEDGES 1000000
#define NIN    4096
#define NOUT   1024
#define BW     64                    // nodes per bucket (dst>>6)
#define NBKT   3125                  // 200000/64 exactly
#define CAP    440                   // slots/(step,bucket); lambda=320, +6.7 sigma
#define CPAD   16                    // counter stride in ints = one 64B line each

// input phase: nodes i < NIN get tanh(x*w_in + bias); rest stay 0 (memset)
__global__ void input_kernel(const float* __restrict__ x,
                             const float* __restrict__ w_in,
                             const float* __restrict__ bias,
                             __half* __restrict__ A0) {
    int tid = blockIdx.x * blockDim.x + threadIdx.x;
    int i = tid >> 6;
    int b = tid & 63;
    if (i >= NIN) return;
    float v = tanhf(x[(size_t)b * NIN + i] * w_in[i] + bias[i]);
    A0[(size_t)i * NB + b] = __float2half(v);
}

// bin 6M edges by (step, dst>>6); record carries src DIRECTLY (no compact pass):
// rec = (dstLocal 6b << 18) | src 18b ; wh = fp16(w) in a parallel array.
// cursors padded to one per 64B line to kill atomic line serialization.
__global__ void binA_kernel(const int* __restrict__ dst,
                            const int* __restrict__ src,
                            const float* __restrict__ wE,
                            int* __restrict__ cnt,        // [NSTEPS*NBKT*CPAD]
                            unsigned* __restrict__ rec,   // [NSTEPS*NBKT][CAP]
                            __half* __restrict__ wh) {    // [NSTEPS*NBKT][CAP]
    int e = blockIdx.x * blockDim.x + threadIdx.x;
    if (e >= NSTEPS * NEDGES) return;
    int s = e / NEDGES;              // magic-mul
    int d = dst[e];
    int bkt = s * NBKT + (d >> 6);
    int pos = atomicAdd(&cnt[bkt * CPAD], 1);
    if (pos < CAP) {
        size_t slot = (size_t)bkt * CAP + pos;
        rec[slot] = ((unsigned)(d & 63) << 18) | (unsigned)src[e];
        wh[slot]  = __float2half(wE[e]);
    }
}

// one block per bucket: fp32 LDS accumulate over 64 nodes; waves consume
// 4-record groups via wave-uniform loads -> 4 independent gathers in flight;
// ds_add_f32 (2-way, free); fused tanh update + ping-pong write.
__global__ __launch_bounds__(256) void step_kernel(
        const float* __restrict__ bias,
        const int* __restrict__ cnt,       // this step, padded
        const unsigned* __restrict__ rec,  // this step: [NBKT][CAP]
        const __half* __restrict__ wh,     // this step: [NBKT][CAP]
        const __half* __restrict__ Aold,
        __half* __restrict__ Anew) {
    __shared__ float acc[BW * NB];         // 16 KB -> 8 blocks/CU
    __shared__ int   flag[BW];
    int bkt  = blockIdx.x;
    int t    = threadIdx.x;
    int lane = t & 63;
    int wid  = t >> 6;

    for (int i = t; i < BW * NB; i += 256) acc[i] = 0.f;
    if (t < BW) flag[t] = 0;
    __syncthreads();

    int m = cnt[bkt * CPAD]; if (m > CAP) m = CAP;
    size_t base = (size_t)bkt * CAP;                  // CAP=440 -> 4-aligned
    const uint4* rec4 = (const uint4*)(rec + base);   // 16B-aligned groups
    const uint2* wh4  = (const uint2*)(wh + base);    // 4 halves per group

    int ngroups = (m + 3) >> 2;
    for (int g = wid; g < ngroups; g += 4) {          // wave-uniform walk
        uint4 r4 = rec4[g];
        union { uint2 u; __half h[4]; } wu; wu.u = wh4[g];
        unsigned ra[4] = { r4.x, r4.y, r4.z, r4.w };
        int rem = m - (g << 2);                       // >= 1
        #pragma unroll
        for (int j = 0; j < 4; ++j) {
            if (j < rem) {
                int sk = (int)(ra[j] & 0x3FFFFu);
                int dl = (int)(ra[j] >> 18);
                float a = __half2float(Aold[((size_t)sk << 6) | lane]);
                atomicAdd(&acc[(dl << 6) | lane], __half2float(wu.h[j]) * a);
                if (lane == 0) flag[dl] = 1;
            }
        }
    }
    __syncthreads();

    int nbase = bkt * BW;
    for (int r = wid; r < BW; r += 4) {
        int n = nbase + r;
        size_t row = ((size_t)n << 6) | lane;
        __half a = Aold[row];
        if (flag[r]) {
            float v = acc[(r << 6) | lane] + bias[n] + __half2float(a);
            Anew[row] = __float2half(tanhf(v));
        } else {
            Anew[row] = a;
        }
    }
}

// out[b][j] = A[N - NOUT + j][b] as fp32
__global__ void output_kernel(const __half* __restrict__ A,
                              float* __restrict__ out) {
    int tid = blockIdx.x * blockDim.x + threadIdx.x;
    if (tid >= NB * NOUT) return;
    int b = tid / NOUT;
    int j = tid % NOUT;
    out[tid] = __half2float(A[(size_t)(NNODES - NOUT + j) * NB + b]);
}

extern "C" void kernel_launch(void* const* d_in, const int* in_sizes, int n_in,
                              void* d_out, int out_size, void* d_ws, size_t ws_size,
                              hipStream_t stream) {
    const float* x      = (const float*)d_in[0];
    const float* w_in   = (const float*)d_in[1];
    const float* bias   = (const float*)d_in[2];
    const float* w_edge = (const float*)d_in[3];   // [S*E] flat
    const int*   src    = (const int*)d_in[4];     // [S*E] flat
    const int*   dst    = (const int*)d_in[5];     // [S*E] flat
    float* out = (float*)d_out;

    // ws: 25.6 + 25.6 + 1.2 + 33.0 + 16.5 = 101.9 MB (<= 103.2 proven safe)
    char* p = (char*)d_ws;
    __half*   A0  = (__half*)p;   p += (size_t)NNODES * NB * 2;
    __half*   A1  = (__half*)p;   p += (size_t)NNODES * NB * 2;
    int*      cnt = (int*)p;      p += (size_t)NSTEPS * NBKT * CPAD * 4;
    unsigned* rec = (unsigned*)p; p += (size_t)NSTEPS * NBKT * CAP * 4;
    __half*   wh  = (__half*)p;

    hipMemsetAsync(A0, 0, (size_t)NNODES * NB * 2, stream);
    hipMemsetAsync(cnt, 0, (size_t)NSTEPS * NBKT * CPAD * 4, stream);

    input_kernel<<<(NIN * NB + 255) / 256, 256, 0, stream>>>(x, w_in, bias, A0);

    const int etot = NSTEPS * NEDGES;
    binA_kernel<<<(etot + 255) / 256, 256, 0, stream>>>(dst, src, w_edge, cnt, rec, wh);

    __half* curA = A0; __half* nxtA = A1;
    for (int s = 0; s < NSTEPS; ++s) {
        step_kernel<<<NBKT, 256, 0, stream>>>(
            bias,
            cnt + (size_t)s * NBKT * CPAD,
            rec + (size_t)s * NBKT * CAP,
            wh  + (size_t)s * NBKT * CAP,
            curA, nxtA);
        __half* tmp = curA; curA = nxtA; nxtA = tmp;
    }

    output_kernel<<<(NB * NOUT + 255) / 256, 256, 0, stream>>>(curA, out);
}

// Round 9
// 809.871 us; speedup vs baseline: 3.3000x; 3.3000x over previous
//
#include <hip/hip_runtime.h>
#include <hip/hip_fp16.h>

#define NB      64        // batch
#define NNODES  200000
#define NSTEPS  6
#define NEDGES  1000000
#define NIN     4096
#define NOUT    1024
#define NC      391                   // coarse buckets of 512 nodes (dst>>9)
#define NCP     512                   // padded coarse count (hist/scan width)
#define CWID    512                   // nodes per coarse bucket
#define CAPC    3072                  // slots per (step,coarse); lambda=2560, +10 sigma
#define CHUNK   8000                  // edges per pass-1 block (1M = 125 * 8000)
#define CPS     125                   // chunks per step
#define NODESP  (NC * CWID)           // 200192 padded node count for off2 rows

// input phase: nodes i < NIN get tanh(x*w_in + bias); rest stay 0 (memset)
__global__ void input_kernel(const float* __restrict__ x,
                             const float* __restrict__ w_in,
                             const float* __restrict__ bias,
                             __half* __restrict__ A0) {
    int tid = blockIdx.x * blockDim.x + threadIdx.x;
    int i = tid >> 6;
    int b = tid & 63;
    if (i >= NIN) return;
    float v = tanhf(x[(size_t)b * NIN + i] * w_in[i] + bias[i]);
    A0[(size_t)i * NB + b] = __float2half(v);
}

// -------- pass 1: chunk-local counting sort by coarse bucket, coalesced flush
// record = (dstLocal 9b << 20) | edgeLocal 20b
__global__ __launch_bounds__(256) void pass1_kernel(
        const int* __restrict__ dst,
        int* __restrict__ gcnt,          // [NSTEPS][NCP]
        unsigned* __restrict__ stage1) { // [NSTEPS][NC][CAPC]
    __shared__ unsigned staged[CHUNK];
    __shared__ int hist[NCP], excl[NCP], cur[NCP], gbase[NC];
    __shared__ int wsum[4];
    int t = threadIdx.x, lane = t & 63, wid = t >> 6;
    int s = blockIdx.x / CPS;
    int chunk = blockIdx.x - s * CPS;
    int e0 = chunk * CHUNK;                       // step-local base
    const int* dstS = dst + (size_t)s * NEDGES;

    hist[t] = 0; hist[t + 256] = 0;
    __syncthreads();
    for (int i = t; i < CHUNK; i += 256)
        atomicAdd(&hist[dstS[e0 + i] >> 9], 1);
    __syncthreads();

    // exclusive scan of hist[0..511] (2 entries/thread + shfl wave scan)
    int a = hist[2 * t], b = hist[2 * t + 1];
    int pair = a + b, v = pair;
    for (int off = 1; off < 64; off <<= 1) {
        int u = __shfl_up(v, off);
        if (lane >= off) v += u;
    }
    if (lane == 63) wsum[wid] = v;
    __syncthreads();
    int woff = 0;
    for (int w2 = 0; w2 < wid; w2++) woff += wsum[w2];
    int epair = v - pair + woff;
    excl[2 * t] = epair;         cur[2 * t] = epair;
    excl[2 * t + 1] = epair + a; cur[2 * t + 1] = epair + a;
    __syncthreads();

    // scatter into LDS sorted-by-coarse order
    for (int i = t; i < CHUNK; i += 256) {
        int d = dstS[e0 + i];                      // L2-hot re-read
        int pos = atomicAdd(&cur[d >> 9], 1);
        staged[pos] = ((unsigned)(d & 511) << 20) | (unsigned)(e0 + i);
    }
    __syncthreads();

    // reserve global space per bucket (parallel), then copy runs coalesced
    for (int c = t; c < NC; c += 256) {
        int len = hist[c];
        gbase[c] = len ? atomicAdd(&gcnt[s * NCP + c], len) : 0;
    }
    __syncthreads();
    for (int c = wid; c < NC; c += 4) {
        int len = hist[c];
        if (!len) continue;
        int st = excl[c], gb = gbase[c];
        int room = CAPC - gb; if (room < 0) room = 0;
        if (len > room) len = room;                // overflow clamp (P ~ 0)
        unsigned* g = stage1 + ((size_t)(s * NC + c)) * CAPC + gb;
        for (int j = lane; j < len; j += 64) g[j] = staged[st + j];
    }
}

// -------- pass 2: per (step,coarse) counting sort by node; emit (src,w) records
// + per-node absolute offset pairs. final record = uint2{src, w_fp32_bits}
__global__ __launch_bounds__(256) void pass2_kernel(
        const unsigned* __restrict__ stage1S,  // this step: [NC][CAPC]
        const int* __restrict__ gcntS,         // this step: [NCP]
        const int* __restrict__ srcS,
        const float* __restrict__ wS,
        uint2* __restrict__ finalR,            // [NC][CAPC] (shared across steps)
        uint2* __restrict__ off2S) {           // this step: [NODESP]
    __shared__ unsigned staged[CAPC];
    __shared__ int hist[CWID], excl[CWID], cur[CWID];
    __shared__ int wsum[4];
    int t = threadIdx.x, lane = t & 63, wid = t >> 6;
    int c = blockIdx.x;
    int m = gcntS[c]; if (m > CAPC) m = CAPC;
    const unsigned* g = stage1S + (size_t)c * CAPC;

    hist[t] = 0; hist[t + 256] = 0;
    __syncthreads();
    for (int i = t; i < m; i += 256) {
        unsigned r = g[i];                   // coalesced
        staged[i] = r;
        atomicAdd(&hist[r >> 20], 1);
    }
    __syncthreads();

    int a = hist[2 * t], b = hist[2 * t + 1];
    int pair = a + b, v = pair;
    for (int off = 1; off < 64; off <<= 1) {
        int u = __shfl_up(v, off);
        if (lane >= off) v += u;
    }
    if (lane == 63) wsum[wid] = v;
    __syncthreads();
    int woff = 0;
    for (int w2 = 0; w2 < wid; w2++) woff += wsum[w2];
    int epair = v - pair + woff;
    excl[2 * t] = epair;         cur[2 * t] = epair;
    excl[2 * t + 1] = epair + a; cur[2 * t + 1] = epair + a;
    __syncthreads();

    // per-node absolute (start,end) into finalR
    int base = c * CAPC;
    for (int dl = t; dl < CWID; dl += 256) {
        int s1 = base + excl[dl];
        off2S[c * CWID + dl] = make_uint2((unsigned)s1, (unsigned)(s1 + hist[dl]));
    }

    // scatter resolved records (random reads stay in L2; writes in 12KB region)
    for (int i = t; i < m; i += 256) {
        unsigned r = staged[i];
        int dl = (int)(r >> 20);
        int el = (int)(r & 0xFFFFFu);
        int pos = base + atomicAdd(&cur[dl], 1);
        finalR[pos] = make_uint2((unsigned)srcS[el], __float_as_uint(wS[el]));
    }
}

// -------- pull: wave per node; one s_load_dwordx2 per edge -> gather -> FMA
__global__ __launch_bounds__(256) void pull_kernel(
        const float* __restrict__ bias,
        const uint2* __restrict__ rec,     // [NC*CAPC]
        const uint2* __restrict__ off2S,   // this step: [NODESP]
        const __half* __restrict__ Aold,
        __half* __restrict__ Anew) {
    int gw = (int)((blockIdx.x * 256 + threadIdx.x) >> 6);
    int lane = threadIdx.x & 63;
    int n = __builtin_amdgcn_readfirstlane(gw);   // wave-uniform -> scalar path
    if (n >= NNODES) return;
    size_t row = ((size_t)n << 6) | lane;
    __half aold = Aold[row];
    uint2 o = off2S[n];
    if (o.x == o.y) { Anew[row] = aold; return; } // no fan-in: keep state
    float acc = __half2float(aold) + bias[n];
    for (unsigned k = o.x; k < o.y; ++k) {
        uint2 q = rec[k];                          // s_load_dwordx2 (uniform)
        acc += __uint_as_float(q.y) *
               __half2float(Aold[((size_t)q.x << 6) | lane]);
    }
    Anew[row] = __float2half(tanhf(acc));
}

// out[b][j] = A[N - NOUT + j][b] as fp32
__global__ void output_kernel(const __half* __restrict__ A,
                              float* __restrict__ out) {
    int tid = blockIdx.x * blockDim.x + threadIdx.x;
    if (tid >= NB * NOUT) return;
    int b = tid / NOUT;
    int j = tid % NOUT;
    out[tid] = __half2float(A[(size_t)(NNODES - NOUT + j) * NB + b]);
}

extern "C" void kernel_launch(void* const* d_in, const int* in_sizes, int n_in,
                              void* d_out, int out_size, void* d_ws, size_t ws_size,
                              hipStream_t stream) {
    const float* x      = (const float*)d_in[0];
    const float* w_in   = (const float*)d_in[1];
    const float* bias   = (const float*)d_in[2];
    const float* w_edge = (const float*)d_in[3];   // [S*E] flat
    const int*   src    = (const int*)d_in[4];     // [S*E] flat
    const int*   dst    = (const int*)d_in[5];     // [S*E] flat
    float* out = (float*)d_out;

    // ws: 25.6+25.6+0.012+28.8+9.6+9.6 = 99.3 MB (<= 103.2 proven safe)
    char* p = (char*)d_ws;
    __half*   A0     = (__half*)p;   p += (size_t)NNODES * NB * 2;
    __half*   A1     = (__half*)p;   p += (size_t)NNODES * NB * 2;
    int*      gcnt   = (int*)p;      p += (size_t)NSTEPS * NCP * 4;
    unsigned* stage1 = (unsigned*)p; p += (size_t)NSTEPS * NC * CAPC * 4;
    uint2*    finalR = (uint2*)p;    p += (size_t)NC * CAPC * 8;
    uint2*    off2   = (uint2*)p;    // [NSTEPS][NODESP]

    hipMemsetAsync(A0, 0, (size_t)NNODES * NB * 2, stream);
    hipMemsetAsync(gcnt, 0, (size_t)NSTEPS * NCP * 4, stream);

    input_kernel<<<(NIN * NB + 255) / 256, 256, 0, stream>>>(x, w_in, bias, A0);

    pass1_kernel<<<NSTEPS * CPS, 256, 0, stream>>>(dst, gcnt, stage1);

    const int pblocks = (NNODES * NB) / 256;   // 50000 blocks = 200K waves
    __half* curA = A0; __half* nxtA = A1;
    for (int s = 0; s < NSTEPS; ++s) {
        pass2_kernel<<<NC, 256, 0, stream>>>(
            stage1 + (size_t)s * NC * CAPC,
            gcnt + (size_t)s * NCP,
            src + (size_t)s * NEDGES,
            w_edge + (size_t)s * NEDGES,
            finalR,
            off2 + (size_t)s * NODESP);
        pull_kernel<<<pblocks, 256, 0, stream>>>(
            bias, finalR, off2 + (size_t)s * NODESP, curA, nxtA);
        __half* tmp = curA; curA = nxtA; nxtA = tmp;
    }

    output_kernel<<<(NB * NOUT + 255) / 256, 256, 0, stream>>>(curA, out);
}

// Round 10
// 671.669 us; speedup vs baseline: 3.9790x; 1.2058x over previous
//
#include <hip/hip_runtime.h>
#include <hip/hip_fp16.h>

#define NB      64        // batch
#define NNODES  200000
#define NSTEPS  6
#define NEDGES  1000000
#define NIN     4096
#define NOUT    1024
#define NC      391                   // coarse buckets of 512 nodes (dst>>9)
#define NCP     512                   // padded coarse count (hist/scan width)
#define CWID    512                   // nodes per coarse bucket
#define CAPC    3072                  // slots per (step,coarse); lambda=2560, +10 sigma
#define CHUNK   8000                  // edges per pass-1 block (1M = 125 * 8000)
#define CPS     125                   // chunks per step
#define NODESP  (NC * CWID)           // 200192 padded node count for off2 rows

// input phase: nodes i < NIN get tanh(x*w_in + bias); rest stay 0 (memset)
__global__ void input_kernel(const float* __restrict__ x,
                             const float* __restrict__ w_in,
                             const float* __restrict__ bias,
                             __half* __restrict__ A0) {
    int tid = blockIdx.x * blockDim.x + threadIdx.x;
    int i = tid >> 6;
    int b = tid & 63;
    if (i >= NIN) return;
    float v = tanhf(x[(size_t)b * NIN + i] * w_in[i] + bias[i]);
    A0[(size_t)i * NB + b] = __float2half(v);
}

// -------- pass 1: chunk-local counting sort by coarse bucket, coalesced flush
// record = (dstLocal 9b << 20) | edgeLocal 20b
__global__ __launch_bounds__(256) void pass1_kernel(
        const int* __restrict__ dst,
        int* __restrict__ gcnt,          // [NSTEPS][NCP]
        unsigned* __restrict__ stage1) { // [NSTEPS][NC][CAPC]
    __shared__ unsigned staged[CHUNK];
    __shared__ int hist[NCP], excl[NCP], cur[NCP], gbase[NC];
    __shared__ int wsum[4];
    int t = threadIdx.x, lane = t & 63, wid = t >> 6;
    int s = blockIdx.x / CPS;
    int chunk = blockIdx.x - s * CPS;
    int e0 = chunk * CHUNK;                       // step-local base
    const int* dstS = dst + (size_t)s * NEDGES;

    hist[t] = 0; hist[t + 256] = 0;
    __syncthreads();
    for (int i = t; i < CHUNK; i += 256)
        atomicAdd(&hist[dstS[e0 + i] >> 9], 1);
    __syncthreads();

    // exclusive scan of hist[0..511] (2 entries/thread + shfl wave scan)
    int a = hist[2 * t], b = hist[2 * t + 1];
    int pair = a + b, v = pair;
    for (int off = 1; off < 64; off <<= 1) {
        int u = __shfl_up(v, off);
        if (lane >= off) v += u;
    }
    if (lane == 63) wsum[wid] = v;
    __syncthreads();
    int woff = 0;
    for (int w2 = 0; w2 < wid; w2++) woff += wsum[w2];
    int epair = v - pair + woff;
    excl[2 * t] = epair;         cur[2 * t] = epair;
    excl[2 * t + 1] = epair + a; cur[2 * t + 1] = epair + a;
    __syncthreads();

    // scatter into LDS sorted-by-coarse order
    for (int i = t; i < CHUNK; i += 256) {
        int d = dstS[e0 + i];                      // L2-hot re-read
        int pos = atomicAdd(&cur[d >> 9], 1);
        staged[pos] = ((unsigned)(d & 511) << 20) | (unsigned)(e0 + i);
    }
    __syncthreads();

    // reserve global space per bucket (parallel), then copy runs coalesced
    for (int c = t; c < NC; c += 256) {
        int len = hist[c];
        gbase[c] = len ? atomicAdd(&gcnt[s * NCP + c], len) : 0;
    }
    __syncthreads();
    for (int c = wid; c < NC; c += 4) {
        int len = hist[c];
        if (!len) continue;
        int st = excl[c], gb = gbase[c];
        int room = CAPC - gb; if (room < 0) room = 0;
        if (len > room) len = room;                // overflow clamp (P ~ 0)
        unsigned* g = stage1 + ((size_t)(s * NC + c)) * CAPC + gb;
        for (int j = lane; j < len; j += 64) g[j] = staged[st + j];
    }
}

// -------- pass 2: per (step,coarse) counting sort by node; emit (src,w) records
// + per-node absolute offset pairs. final record = uint2{src, w_fp32_bits}
__global__ __launch_bounds__(256) void pass2_kernel(
        const unsigned* __restrict__ stage1S,  // this step: [NC][CAPC]
        const int* __restrict__ gcntS,         // this step: [NCP]
        const int* __restrict__ srcS,
        const float* __restrict__ wS,
        uint2* __restrict__ finalR,            // [NC][CAPC] (shared across steps)
        uint2* __restrict__ off2S,             // this step: [NODESP]
        int cBase) {
    __shared__ unsigned staged[CAPC];
    __shared__ int hist[CWID], excl[CWID], cur[CWID];
    __shared__ int wsum[4];
    int t = threadIdx.x, lane = t & 63, wid = t >> 6;
    int c = blockIdx.x + cBase;
    int m = gcntS[c]; if (m > CAPC) m = CAPC;
    const unsigned* g = stage1S + (size_t)c * CAPC;

    hist[t] = 0; hist[t + 256] = 0;
    __syncthreads();
    for (int i = t; i < m; i += 256) {
        unsigned r = g[i];                   // coalesced
        staged[i] = r;
        atomicAdd(&hist[r >> 20], 1);
    }
    __syncthreads();

    int a = hist[2 * t], b = hist[2 * t + 1];
    int pair = a + b, v = pair;
    for (int off = 1; off < 64; off <<= 1) {
        int u = __shfl_up(v, off);
        if (lane >= off) v += u;
    }
    if (lane == 63) wsum[wid] = v;
    __syncthreads();
    int woff = 0;
    for (int w2 = 0; w2 < wid; w2++) woff += wsum[w2];
    int epair = v - pair + woff;
    excl[2 * t] = epair;         cur[2 * t] = epair;
    excl[2 * t + 1] = epair + a; cur[2 * t + 1] = epair + a;
    __syncthreads();

    // per-node absolute (start,end) into finalR
    int base = c * CAPC;
    for (int dl = t; dl < CWID; dl += 256) {
        int s1 = base + excl[dl];
        off2S[c * CWID + dl] = make_uint2((unsigned)s1, (unsigned)(s1 + hist[dl]));
    }

    // scatter resolved records (random reads stay in L2; writes in 12KB region)
    for (int i = t; i < m; i += 256) {
        unsigned r = staged[i];
        int dl = (int)(r >> 20);
        int el = (int)(r & 0xFFFFFu);
        int pos = base + atomicAdd(&cur[dl], 1);
        finalR[pos] = make_uint2((unsigned)srcS[el], __float_as_uint(wS[el]));
    }
}

// -------- pull: wave per 2 nodes (2 lists interleaved -> 2 gathers in flight);
// srcLimit skips gathers from provably-zero sources (step 0: src >= NIN)
__global__ __launch_bounds__(256) void pull_kernel(
        const float* __restrict__ bias,
        const uint2* __restrict__ rec,     // [NC*CAPC]
        const uint2* __restrict__ off2S,   // this step: [NODESP]
        const __half* __restrict__ Aold,
        __half* __restrict__ Anew,
        int nodeBase, int nodeEnd, int srcLimit) {
    int gw = (int)((blockIdx.x * 256 + threadIdx.x) >> 6);
    int lane = threadIdx.x & 63;
    int n0 = nodeBase + 2 * __builtin_amdgcn_readfirstlane(gw);
    if (n0 >= nodeEnd) return;
    int n1 = n0 + 1;
    size_t row0 = ((size_t)n0 << 6) | lane;
    size_t row1 = row0 + NB;
    __half a0 = Aold[row0], a1 = Aold[row1];
    uint2 o0 = off2S[n0], o1 = off2S[n1];
    bool upd0 = (o0.x != o0.y), upd1 = (o1.x != o1.y);
    float acc0 = __half2float(a0) + bias[n0];
    float acc1 = __half2float(a1) + bias[n1];
    unsigned k0 = o0.x, k1 = o1.x;
    while (k0 < o0.y || k1 < o1.y) {
        bool h0 = k0 < o0.y, h1 = k1 < o1.y;
        uint2 q0, q1;
        float g0 = 0.f, g1 = 0.f;
        if (h0) q0 = rec[k0++];                    // s_load_dwordx2 (uniform)
        if (h1) q1 = rec[k1++];
        if (h0 && (int)q0.x < srcLimit)
            g0 = __uint_as_float(q0.y) * __half2float(Aold[((size_t)q0.x << 6) | lane]);
        if (h1 && (int)q1.x < srcLimit)
            g1 = __uint_as_float(q1.y) * __half2float(Aold[((size_t)q1.x << 6) | lane]);
        acc0 += g0; acc1 += g1;
    }
    Anew[row0] = upd0 ? __float2half(tanhf(acc0)) : a0;
    Anew[row1] = upd1 ? __float2half(tanhf(acc1)) : a1;
}

// out[b][j] = A[N - NOUT + j][b] as fp32
__global__ void output_kernel(const __half* __restrict__ A,
                              float* __restrict__ out) {
    int tid = blockIdx.x * blockDim.x + threadIdx.x;
    if (tid >= NB * NOUT) return;
    int b = tid / NOUT;
    int j = tid % NOUT;
    out[tid] = __half2float(A[(size_t)(NNODES - NOUT + j) * NB + b]);
}

extern "C" void kernel_launch(void* const* d_in, const int* in_sizes, int n_in,
                              void* d_out, int out_size, void* d_ws, size_t ws_size,
                              hipStream_t stream) {
    const float* x      = (const float*)d_in[0];
    const float* w_in   = (const float*)d_in[1];
    const float* bias   = (const float*)d_in[2];
    const float* w_edge = (const float*)d_in[3];   // [S*E] flat
    const int*   src    = (const int*)d_in[4];     // [S*E] flat
    const int*   dst    = (const int*)d_in[5];     // [S*E] flat
    float* out = (float*)d_out;

    // ws: 25.6+25.6+0.012+28.8+9.6+9.6 = 99.3 MB (<= 103.2 proven safe)
    char* p = (char*)d_ws;
    __half*   A0     = (__half*)p;   p += (size_t)NNODES * NB * 2;
    __half*   A1     = (__half*)p;   p += (size_t)NNODES * NB * 2;
    int*      gcnt   = (int*)p;      p += (size_t)NSTEPS * NCP * 4;
    unsigned* stage1 = (unsigned*)p; p += (size_t)NSTEPS * NC * CAPC * 4;
    uint2*    finalR = (uint2*)p;    p += (size_t)NC * CAPC * 8;
    uint2*    off2   = (uint2*)p;    // [NSTEPS][NODESP]

    hipMemsetAsync(A0, 0, (size_t)NNODES * NB * 2, stream);
    hipMemsetAsync(gcnt, 0, (size_t)NSTEPS * NCP * 4, stream);

    input_kernel<<<(NIN * NB + 255) / 256, 256, 0, stream>>>(x, w_in, bias, A0);

    pass1_kernel<<<NSTEPS * CPS, 256, 0, stream>>>(dst, gcnt, stage1);

    __half* curA = A0; __half* nxtA = A1;
    for (int s = 0; s < NSTEPS; ++s) {
        bool last = (s == NSTEPS - 1);
        int cBase   = last ? (NNODES - NOUT) >> 9 : 0;        // 388
        int cBlocks = last ? NC - cBase : NC;                 // 3 or 391
        pass2_kernel<<<cBlocks, 256, 0, stream>>>(
            stage1 + (size_t)s * NC * CAPC,
            gcnt + (size_t)s * NCP,
            src + (size_t)s * NEDGES,
            w_edge + (size_t)s * NEDGES,
            finalR,
            off2 + (size_t)s * NODESP,
            cBase);
        int nodeBase = last ? NNODES - NOUT : 0;
        int nodeCnt  = last ? NOUT : NNODES;
        int srcLimit = (s == 0) ? NIN : NNODES;
        pull_kernel<<<nodeCnt / 8, 256, 0, stream>>>(
            bias, finalR, off2 + (size_t)s * NODESP, curA, nxtA,
            nodeBase, nodeBase + nodeCnt, srcLimit);
        __half* tmp = curA; curA = nxtA; nxtA = tmp;
    }

    output_kernel<<<(NB * NOUT + 255) / 256, 256, 0, stream>>>(curA, out);
}